// Round 5
// baseline (315.509 us; speedup 1.0000x reference)
//
#include <hip/hip_runtime.h>

// AR(16) sequence generation, out (B=4096, T=8192) fp32.
// R5: the R0-R4 kernels all spilled (VGPR_Count=32 vs >=64 live floats) ->
// scratch traffic + dead prefetch was the real bottleneck, not TLP.
// Fixes: coeffs in SGPR (readfirstlane), chunk 16->8 with a pipelined pair
// loop (8 loads always in flight, 16 buffer regs), launch_bounds(256,4) for a
// 128-VGPR budget. SEG_L=W=128 (2x work; logical noise reads 256 MB).

#define SEG_L 128   // main (output-producing) steps per segment
#define SEG_W 128   // zero-state warmup steps (contraction 0.909^128 ~ 5e-6)
#define CH 8        // steps per load-chunk

// One recurrence step. Window invariant: at rotation k, y[t-16+i] == w[(k+i)&15].
// Dependent terms (i=14,15) applied LAST: per-step critical path ~2 FMA lat.
__device__ __forceinline__ float arstep(const float (&c)[16], const float (&w)[16],
                                        int k, float e) {
    float p0 = fmaf(c[0],  w[(k + 0)  & 15], e);
    float p1 =      c[1] * w[(k + 1)  & 15];
    float p2 =      c[2] * w[(k + 2)  & 15];
    float p3 =      c[3] * w[(k + 3)  & 15];
    p0 = fmaf(c[4],  w[(k + 4)  & 15], p0);
    p1 = fmaf(c[5],  w[(k + 5)  & 15], p1);
    p2 = fmaf(c[6],  w[(k + 6)  & 15], p2);
    p3 = fmaf(c[7],  w[(k + 7)  & 15], p3);
    p0 = fmaf(c[8],  w[(k + 8)  & 15], p0);
    p1 = fmaf(c[9],  w[(k + 9)  & 15], p1);
    p2 = fmaf(c[10], w[(k + 10) & 15], p2);
    p3 = fmaf(c[11], w[(k + 11) & 15], p3);
    p0 = fmaf(c[12], w[(k + 12) & 15], p0);
    p1 = fmaf(c[13], w[(k + 13) & 15], p1);
    p0 += p2;
    p1 += p3;
    p0 += p1;
    p0 = fmaf(c[14], w[(k + 14) & 15], p0);   // critical-path tail
    return fmaf(c[15], w[(k + 15) & 15], p0); // newest value last
}

// CH strided loads (one chunk of noise for this lane), pre-scaled by nstd.
__device__ __forceinline__ void loadch(float (&buf)[CH], const float* __restrict__ p,
                                       int B, float nstd) {
#pragma unroll
    for (int j = 0; j < CH; ++j) buf[j] = p[(size_t)j * B] * nstd;
}

__global__ __launch_bounds__(256, 4)
void ARModel_27925877359180_kernel(const float* __restrict__ init,   // (B,16)
                                   const float* __restrict__ coeff,  // (16)
                                   const float* __restrict__ lns,    // (1)
                                   const float* __restrict__ noise,  // (TN,B)
                                   float* __restrict__ out,          // (B,T)
                                   int B, int TN, int T, int nbc)
{
    const int blk = blockIdx.x;
    const int s   = blk / nbc;                       // segment index
    const int b   = (blk % nbc) * blockDim.x + threadIdx.x;
    if (b >= B) return;

    // coefficients are wave-uniform: pin them to SGPRs (frees 16 VGPRs)
    float c[16];
#pragma unroll
    for (int i = 0; i < 16; ++i)
        c[i] = __int_as_float(__builtin_amdgcn_readfirstlane(__float_as_int(coeff[i])));
    const float nstd = expf(__int_as_float(
        __builtin_amdgcn_readfirstlane(__float_as_int(lns[0]))));

    const int start    = s * SEG_L;                  // first main noise index
    const int len      = min(SEG_L, TN - start);     // 128, tail 112
    const bool useInit = (start <= SEG_W);           // exact warmup from t=0
    const int wsteps   = useInit ? start : SEG_W;    // 0 or 128

    float w[16];
    if (useInit) {
        const float4* i4 = (const float4*)(init + (size_t)b * 16);
        float4 a0 = i4[0], a1 = i4[1], a2 = i4[2], a3 = i4[3];
        w[0]  = a0.x; w[1]  = a0.y; w[2]  = a0.z; w[3]  = a0.w;
        w[4]  = a1.x; w[5]  = a1.y; w[6]  = a1.z; w[7]  = a1.w;
        w[8]  = a2.x; w[9]  = a2.y; w[10] = a2.z; w[11] = a2.w;
        w[12] = a3.x; w[13] = a3.y; w[14] = a3.z; w[15] = a3.w;
        if (s == 0) {
            float4* o4 = (float4*)(out + (size_t)b * T);
            o4[0] = a0; o4[1] = a1; o4[2] = a2; o4[3] = a3;
        }
    } else {
#pragma unroll
        for (int i = 0; i < 16; ++i) w[i] = 0.0f;
    }

    const int nch = (wsteps + len) / CH;             // always even
    const int npr = nch / 2;                         // pairs of chunks (16 steps)
    const int wpr = wsteps / (2 * CH);               // warmup pairs (no store)
    const float* nbase = noise + (size_t)(start - wsteps) * B + b;
    float* op = out + (size_t)b * T + 16 + start;

    float A[CH], Bf[CH];
    loadch(A, nbase, B, nstd);                       // chunk 0

    for (int pr = 0; pr < npr; ++pr) {
        // prefetch chunk 2pr+1 while computing chunk 2pr (window base 0)
        loadch(Bf, nbase + (size_t)(2 * pr + 1) * (CH * B), B, nstd);
#pragma unroll
        for (int j = 0; j < CH; ++j) w[j] = arstep(c, w, j, A[j]);
        // prefetch chunk 2pr+2 (clamped) while computing chunk 2pr+1 (base 8)
        loadch(A, nbase + (size_t)min(2 * pr + 2, nch - 1) * (CH * B), B, nstd);
#pragma unroll
        for (int j = 0; j < CH; ++j) w[CH + j] = arstep(c, w, CH + j, Bf[j]);
        if (pr >= wpr) {                             // w[0..15] chronological
            float4* o4 = (float4*)op;
#pragma unroll
            for (int q = 0; q < 4; ++q) o4[q] = ((const float4*)w)[q];
            op += 16;
        }
    }
}

extern "C" void kernel_launch(void* const* d_in, const int* in_sizes, int n_in,
                              void* d_out, int out_size, void* d_ws, size_t ws_size,
                              hipStream_t stream) {
    const float* init  = (const float*)d_in[0];   // (B,16)
    const float* coeff = (const float*)d_in[1];   // (16)
    const float* lns   = (const float*)d_in[2];   // (1)
    const float* noise = (const float*)d_in[3];   // (TN,B)
    float* out = (float*)d_out;                   // (B,T) fp32

    const int B   = in_sizes[0] / 16;             // 4096
    const int TN  = in_sizes[3] / B;              // 8176
    const int T   = TN + 16;                      // 8192
    const int S   = (TN + SEG_L - 1) / SEG_L;     // 64
    const int nbc = (B + 255) / 256;              // 16

    dim3 grid(nbc * S), block(256);
    hipLaunchKernelGGL(ARModel_27925877359180_kernel, grid, block, 0, stream,
                       init, coeff, lns, noise, out, B, TN, T, nbc);
}